// Round 1
// baseline (1772.311 us; speedup 1.0000x reference)
//
#include <hip/hip_runtime.h>
#include <math.h>
#include <stdint.h>

#define BATCH 64
#define N 128
#define DIM 64

// Monotone float->uint mapping (order-preserving for all finite floats and +inf)
__device__ __forceinline__ unsigned monokey(float x) {
    unsigned b = __float_as_uint(x);
    return (b & 0x80000000u) ? ~b : (b | 0x80000000u);
}
__device__ __forceinline__ float monoval(unsigned k) {
    unsigned b = (k & 0x80000000u) ? (k & 0x7FFFFFFFu) : ~k;
    return __uint_as_float(b);
}

__device__ __forceinline__ unsigned long long shfl_xor_u64(unsigned long long x, int m) {
    unsigned lo = (unsigned)(x & 0xFFFFFFFFull);
    unsigned hi = (unsigned)(x >> 32);
    lo = __shfl_xor(lo, m);
    hi = __shfl_xor(hi, m);
    return ((unsigned long long)hi << 32) | lo;
}

// One block per batch. 128 threads (2 waves). Thread tid owns column j = tid+1 (1-based).
__global__ __launch_bounds__(128)
void lsap_kernel(const float* __restrict__ y_true, const float* __restrict__ y_pred,
                 float* __restrict__ batch_sums, float* __restrict__ out, int use_atomic) {
    __shared__ float dist[N * N];        // 64 KB
    __shared__ float ytl[N * DIM];       // 32 KB
    __shared__ float u_lds[N + 1];
    __shared__ int   p_lds[N + 1];
    __shared__ int   way_lds[N + 1];
    __shared__ unsigned long long red[2];
    __shared__ float sred[2];

    const int b = blockIdx.x;
    const int tid = threadIdx.x;

    // ---- stage y_true[b] into LDS (coalesced float4) ----
    {
        const float4* yt4 = (const float4*)(y_true + (size_t)b * N * DIM);
        float4* ytl4 = (float4*)ytl;
        for (int k = tid; k < N * DIM / 4; k += 128) ytl4[k] = yt4[k];
    }

    // ---- load y_pred row `tid` into registers ----
    float ypr[DIM];
    {
        const float4* yp4 = (const float4*)(y_pred + (size_t)b * N * DIM + (size_t)tid * DIM);
        #pragma unroll
        for (int k = 0; k < DIM / 4; ++k) {
            float4 v4 = yp4[k];
            ypr[4*k+0] = v4.x; ypr[4*k+1] = v4.y; ypr[4*k+2] = v4.z; ypr[4*k+3] = v4.w;
        }
    }

    // init u, p
    for (int k = tid; k <= N; k += 128) { u_lds[k] = 0.f; p_lds[k] = 0; }
    __syncthreads();

    // ---- compute dist[i][tid] = ||y_true[b,i] - y_pred[b,tid]|| for all i ----
    {
        const float4* ytlv = (const float4*)ytl;
        for (int i = 0; i < N; ++i) {
            float acc = 0.f;
            #pragma unroll
            for (int d4 = 0; d4 < DIM / 4; ++d4) {
                float4 t = ytlv[i * (DIM / 4) + d4];
                float df;
                df = t.x - ypr[4*d4+0]; acc = fmaf(df, df, acc);
                df = t.y - ypr[4*d4+1]; acc = fmaf(df, df, acc);
                df = t.z - ypr[4*d4+2]; acc = fmaf(df, df, acc);
                df = t.w - ypr[4*d4+3]; acc = fmaf(df, df, acc);
            }
            dist[i * N + tid] = sqrtf(acc);
        }
    }
    __syncthreads();

    // ---- Jonker-Volgenant (e-maxx formulation), one column per thread ----
    const int j = tid + 1;   // 1-based column owned by this thread
    float v = 0.f;           // v[j] in register (persists across rows)

    for (int i = 1; i <= N; ++i) {
        if (tid == 0) p_lds[0] = i;
        float minv = INFINITY;  // minv[j]
        int used = 0;           // used[j]
        __syncthreads();

        int j0 = 0;
        while (true) {
            // i0 = p[j0]; broadcast LDS reads
            int i0 = p_lds[j0];
            float u_i0 = u_lds[i0];
            if (j == j0) used = 1;

            float cand = INFINITY;
            if (!used) {
                float cur = dist[(i0 - 1) * N + tid] - u_i0 - v;
                if (cur < minv) { minv = cur; way_lds[j] = j0; }
                cand = minv;
            }

            // argmin over unused columns: packed (monotone(val) << 32) | j, min-reduce
            unsigned long long kk = ((unsigned long long)monokey(cand) << 32) | (unsigned)j;
            #pragma unroll
            for (int m = 1; m < 64; m <<= 1) {
                unsigned long long o = shfl_xor_u64(kk, m);
                kk = (o < kk) ? o : kk;
            }
            if ((tid & 63) == 0) red[tid >> 6] = kk;
            __syncthreads();
            {
                unsigned long long k0 = red[0], k1 = red[1];
                kk = (k0 < k1) ? k0 : k1;
            }
            int j1 = (int)(kk & 0xFFFFFFFFu);
            float delta = monoval((unsigned)(kk >> 32));

            // dual updates
            if (used) {
                u_lds[p_lds[j]] += delta;  // distinct rows across used columns
                v -= delta;
            } else {
                minv -= delta;
            }
            if (tid == 0) u_lds[i] += delta;  // column 0: p[0] = i

            j0 = j1;
            __syncthreads();   // make u updates visible; allow red[] reuse
            if (p_lds[j0] == 0) break;
        }

        // ---- augment along alternating path (thread 0, pointer chase in LDS) ----
        if (tid == 0) {
            int jj = j0;
            while (jj != 0) {
                int jprev = way_lds[jj];
                p_lds[jj] = p_lds[jprev];
                jj = jprev;
            }
        }
        __syncthreads();
    }

    // ---- matched sum: sum_j dist[p[j]-1][j-1] ----
    float val = dist[(p_lds[j] - 1) * N + tid];
    #pragma unroll
    for (int m = 1; m < 64; m <<= 1) val += __shfl_xor(val, m);
    if ((tid & 63) == 0) sred[tid >> 6] = val;
    __syncthreads();
    if (tid == 0) {
        float s = sred[0] + sred[1];
        if (use_atomic) {
            atomicAdd(out, s * (1.0f / (float)BATCH));
        } else {
            batch_sums[b] = s;
        }
    }
}

__global__ __launch_bounds__(64)
void reduce_kernel(const float* __restrict__ bs, float* __restrict__ out) {
    int tid = threadIdx.x;
    float v = bs[tid];
    #pragma unroll
    for (int m = 1; m < 64; m <<= 1) v += __shfl_xor(v, m);
    if (tid == 0) out[0] = v * (1.0f / (float)BATCH);
}

extern "C" void kernel_launch(void* const* d_in, const int* in_sizes, int n_in,
                              void* d_out, int out_size, void* d_ws, size_t ws_size,
                              hipStream_t stream) {
    const float* y_true = (const float*)d_in[0];
    const float* y_pred = (const float*)d_in[1];
    float* out = (float*)d_out;

    if (ws_size >= BATCH * sizeof(float)) {
        float* bs = (float*)d_ws;
        lsap_kernel<<<BATCH, 128, 0, stream>>>(y_true, y_pred, bs, out, 0);
        reduce_kernel<<<1, 64, 0, stream>>>(bs, out);
    } else {
        // fallback: zero the scalar then atomically accumulate
        hipMemsetAsync(d_out, 0, sizeof(float), stream);
        lsap_kernel<<<BATCH, 128, 0, stream>>>(y_true, y_pred, nullptr, out, 1);
    }
}

// Round 2
// 734.897 us; speedup vs baseline: 2.4116x; 2.4116x over previous
//
#include <hip/hip_runtime.h>
#include <math.h>
#include <stdint.h>

#define BATCH 64
#define N 128
#define DIM 64

// min over each 16-lane row via DPP rotates (VALU-only), then cross-row via shfl_xor.
__device__ __forceinline__ float wave_min64(float x) {
    int t;
    t = __builtin_amdgcn_update_dpp(0, __float_as_int(x), 0x121, 0xF, 0xF, false); // row_ror:1
    x = fminf(x, __int_as_float(t));
    t = __builtin_amdgcn_update_dpp(0, __float_as_int(x), 0x122, 0xF, 0xF, false); // row_ror:2
    x = fminf(x, __int_as_float(t));
    t = __builtin_amdgcn_update_dpp(0, __float_as_int(x), 0x124, 0xF, 0xF, false); // row_ror:4
    x = fminf(x, __int_as_float(t));
    t = __builtin_amdgcn_update_dpp(0, __float_as_int(x), 0x128, 0xF, 0xF, false); // row_ror:8
    x = fminf(x, __int_as_float(t));
    x = fminf(x, __shfl_xor(x, 16));
    x = fminf(x, __shfl_xor(x, 32));
    return x;  // every lane holds the global min
}

// One block = one batch. 64 threads (1 wave). Lane owns 1-based columns ja=lane+1, jb=lane+65.
__global__ __launch_bounds__(64, 1)
void lsap_kernel(const float* __restrict__ y_true, const float* __restrict__ y_pred,
                 float* __restrict__ batch_sums, float* __restrict__ out, int use_atomic) {
    __shared__ float dist[N * N];        // 64 KB; column c only ever touched by lane c&63
    __shared__ float ytl[N * DIM];       // 32 KB
    __shared__ long long pu[N + 1];      // per column j: low32 = p[j] (row, 1-based; 0=free), high32 = bits of u[p[j]]
    __shared__ int way[N + 1];
    __shared__ float u_row[N];           // greedy-init dual u for each row
    __shared__ int jstar[N];             // argmin column (1-based) per row
    __shared__ int unlist[N];            // rows not assigned greedily
    __shared__ int nun_s;

    const int b = blockIdx.x;
    const int lane = threadIdx.x;
    const int ca = lane, cb = lane + 64;     // 0-based owned columns
    const int ja = lane + 1, jb = lane + 65; // 1-based

    // ---- stage y_true[b] into LDS ----
    {
        const float4* yt4 = (const float4*)(y_true + (size_t)b * N * DIM);
        float4* ytl4 = (float4*)ytl;
        for (int k = lane; k < N * DIM / 4; k += 64) ytl4[k] = yt4[k];
    }

    // ---- y_pred rows ca, cb into registers ----
    float ypa[DIM], ypb[DIM];
    {
        const float4* pa4 = (const float4*)(y_pred + (size_t)b * N * DIM + (size_t)ca * DIM);
        const float4* pb4 = (const float4*)(y_pred + (size_t)b * N * DIM + (size_t)cb * DIM);
        #pragma unroll
        for (int k = 0; k < DIM / 4; ++k) {
            float4 v4 = pa4[k];
            ypa[4*k+0]=v4.x; ypa[4*k+1]=v4.y; ypa[4*k+2]=v4.z; ypa[4*k+3]=v4.w;
            float4 w4 = pb4[k];
            ypb[4*k+0]=w4.x; ypb[4*k+1]=w4.y; ypb[4*k+2]=w4.z; ypb[4*k+3]=w4.w;
        }
    }

    // init pu (p=0 everywhere)
    pu[lane] = 0; pu[lane + 64] = 0;
    if (lane == 0) pu[128] = 0;
    __syncthreads();   // ytl visible to all lanes

    // ---- dist compute (lane writes its 2 columns) fused with column-minima (Phase A) ----
    float va = INFINITY, vb = INFINITY;   // v[ja], v[jb] — live in registers for the whole solve
    for (int i = 0; i < N; ++i) {
        const float4* yr = (const float4*)(ytl + i * DIM);
        float a0 = 0.f, a1 = 0.f;
        #pragma unroll
        for (int k = 0; k < DIM / 4; ++k) {
            float4 t4 = yr[k];
            float d;
            d = t4.x - ypa[4*k+0]; a0 = fmaf(d, d, a0);
            d = t4.y - ypa[4*k+1]; a0 = fmaf(d, d, a0);
            d = t4.z - ypa[4*k+2]; a0 = fmaf(d, d, a0);
            d = t4.w - ypa[4*k+3]; a0 = fmaf(d, d, a0);
            d = t4.x - ypb[4*k+0]; a1 = fmaf(d, d, a1);
            d = t4.y - ypb[4*k+1]; a1 = fmaf(d, d, a1);
            d = t4.z - ypb[4*k+2]; a1 = fmaf(d, d, a1);
            d = t4.w - ypb[4*k+3]; a1 = fmaf(d, d, a1);
        }
        float d0 = sqrtf(a0), d1 = sqrtf(a1);
        dist[i * N + ca] = d0;
        dist[i * N + cb] = d1;
        va = fminf(va, d0);
        vb = fminf(vb, d1);
    }

    // ---- Phase B: row minima of reduced costs; u_row[r] = min_j (c - v), jstar = argmin ----
    for (int r = 0; r < N; ++r) {
        float c0 = dist[r * N + ca] - va;
        float c1 = dist[r * N + cb] - vb;
        float cand = c0; int colm = ja;
        if (c1 < cand) { cand = c1; colm = jb; }
        float g = wave_min64(cand);
        unsigned long long mk = __ballot(cand == g);
        int src = (int)(__ffsll((unsigned long long)mk) - 1);
        int js = __builtin_amdgcn_readlane(colm, src);
        if (lane == 0) { u_row[r] = g; jstar[r] = js; }
    }

    // ---- Phase C: greedy assignment (serial, lane 0) ----
    if (lane == 0) {
        int nun = 0;
        for (int r = 0; r < N; ++r) {
            int js = jstar[r];
            if ((int)pu[js] == 0) {
                pu[js] = ((long long)__float_as_int(u_row[r]) << 32) | (unsigned)(r + 1);
            } else {
                unlist[nun++] = r;
            }
        }
        nun_s = nun;
    }
    __syncthreads();
    const int nun = nun_s;

    // ---- main: Dijkstra augmenting row for each unassigned row ----
    for (int k = 0; k < nun; ++k) {
        __syncthreads();                 // previous row's pu/augment writes visible
        const int r = unlist[k];
        const int i_new = r + 1;
        const float u_i = u_row[r];

        // refresh register copies of (p, u) for owned columns
        long long ta = pu[ja], tb = pu[jb];
        int pa = (int)ta, pb = (int)tb;
        float upa = __int_as_float((int)(ta >> 32));
        float upb = __int_as_float((int)(tb >> 32));

        float mina = INFINITY, minb = INFINITY;
        int useda = 0, usedb = 0;
        float uacca = 0.f, uaccb = 0.f;
        float u_acc_i = u_i;             // running dual for the new row

        int j0 = 0, i0 = i_new;
        float u0c = u_i;

        for (;;) {
            if (ja == j0) useda = 1;
            if (jb == j0) usedb = 1;
            float d0 = dist[(i0 - 1) * N + ca];
            float d1 = dist[(i0 - 1) * N + cb];
            if (!useda) { float cur = d0 - u0c - va; if (cur < mina) { mina = cur; way[ja] = j0; } }
            if (!usedb) { float cur = d1 - u0c - vb; if (cur < minb) { minb = cur; way[jb] = j0; } }

            float cand = useda ? INFINITY : mina;
            int colm = ja, pm = pa; float um = upa;
            float candb = usedb ? INFINITY : minb;
            if (candb < cand) { cand = candb; colm = jb; pm = pb; um = upb; }

            float delta = wave_min64(cand);
            unsigned long long mk = __ballot(cand == delta);
            int src = (int)(__ffsll((unsigned long long)mk) - 1);
            int pk = (pm << 8) | colm;                       // pack (p, j) of the winner
            pk = __builtin_amdgcn_readlane(pk, src);
            float u1 = __int_as_float(__builtin_amdgcn_readlane(__float_as_int(um), src));
            int j1 = pk & 0xFF;
            int i1 = pk >> 8;

            if (useda) { va -= delta; uacca += delta; } else { mina -= delta; }
            if (usedb) { vb -= delta; uaccb += delta; } else { minb -= delta; }
            u_acc_i += delta;

            j0 = j1;
            if (i1 == 0) break;          // reached a free column
            i0 = i1; u0c = u1;
        }

        // deferred dual writes: u[p[j]] += acc for used owned columns
        int* pui = (int*)pu;
        if (useda) pui[2 * ja + 1] = __float_as_int(upa + uacca);
        if (usedb) pui[2 * jb + 1] = __float_as_int(upb + uaccb);
        __syncthreads();                 // way + pu updates visible to lane 0

        if (lane == 0) {
            // augment: move (p,u) pairs backward along the alternating path
            int jj = j0;
            for (;;) {
                int jp = way[jj];
                if (jp == 0) {
                    pu[jj] = ((long long)__float_as_int(u_acc_i) << 32) | (unsigned)i_new;
                    break;
                }
                pu[jj] = pu[jp];
                jj = jp;
            }
        }
    }
    __syncthreads();

    // ---- matched sum ----
    long long ta = pu[ja], tb = pu[jb];
    int pa = (int)ta, pb = (int)tb;
    float s = dist[(pa - 1) * N + ca] + dist[(pb - 1) * N + cb];
    #pragma unroll
    for (int m = 1; m < 64; m <<= 1) s += __shfl_xor(s, m);
    if (lane == 0) {
        if (use_atomic) atomicAdd(out, s * (1.0f / (float)BATCH));
        else batch_sums[b] = s;
    }
}

__global__ __launch_bounds__(64)
void reduce_kernel(const float* __restrict__ bs, float* __restrict__ out) {
    int tid = threadIdx.x;
    float v = bs[tid];
    #pragma unroll
    for (int m = 1; m < 64; m <<= 1) v += __shfl_xor(v, m);
    if (tid == 0) out[0] = v * (1.0f / (float)BATCH);
}

extern "C" void kernel_launch(void* const* d_in, const int* in_sizes, int n_in,
                              void* d_out, int out_size, void* d_ws, size_t ws_size,
                              hipStream_t stream) {
    const float* y_true = (const float*)d_in[0];
    const float* y_pred = (const float*)d_in[1];
    float* out = (float*)d_out;

    if (ws_size >= BATCH * sizeof(float)) {
        float* bs = (float*)d_ws;
        lsap_kernel<<<BATCH, 64, 0, stream>>>(y_true, y_pred, bs, out, 0);
        reduce_kernel<<<1, 64, 0, stream>>>(bs, out);
    } else {
        hipMemsetAsync(d_out, 0, sizeof(float), stream);
        lsap_kernel<<<BATCH, 64, 0, stream>>>(y_true, y_pred, nullptr, out, 1);
    }
}

// Round 3
// 587.212 us; speedup vs baseline: 3.0182x; 1.2515x over previous
//
#include <hip/hip_runtime.h>
#include <math.h>
#include <stdint.h>

#define BATCH 64
#define N 128
#define DIM 64
#define ARR_CAP 384

typedef unsigned uint32x2_t __attribute__((ext_vector_type(2)));

// branchless monotone float->uint (order-preserving incl. +inf)
__device__ __forceinline__ unsigned monokey(float x) {
    unsigned b = __float_as_uint(x);
    return b ^ (unsigned)(((int)b >> 31) | (int)0x80000000u);
}

__device__ __forceinline__ unsigned umin_(unsigned a, unsigned b) { return a < b ? a : b; }
__device__ __forceinline__ unsigned umax_(unsigned a, unsigned b) { return a > b ? a : b; }
__device__ __forceinline__ int rl_i(int v, int l) { return __builtin_amdgcn_readlane(v, l); }
__device__ __forceinline__ float rl_f(float v, int l) {
    return __int_as_float(__builtin_amdgcn_readlane(__float_as_int(v), l));
}

#define DPP_ROR(x, n) __builtin_amdgcn_update_dpp((int)(x), (int)(x), 0x120 + (n), 0xF, 0xF, false)

__device__ __forceinline__ unsigned partner16(unsigned x, int lane) {
#if __has_builtin(__builtin_amdgcn_permlane16_swap)
    uint32x2_t r = __builtin_amdgcn_permlane16_swap(x, x, false, false);
    return (lane & 16) ? r[0] : r[1];
#else
    return (unsigned)__shfl_xor((int)x, 16);
#endif
}
__device__ __forceinline__ unsigned partner32(unsigned x, int lane) {
#if __has_builtin(__builtin_amdgcn_permlane32_swap)
    uint32x2_t r = __builtin_amdgcn_permlane32_swap(x, x, false, false);
    return (lane & 32) ? r[0] : r[1];
#else
    return (unsigned)__shfl_xor((int)x, 32);
#endif
}

// full-wave min of packed keys; every lane gets the result. VALU-only.
__device__ __forceinline__ unsigned wave_kmin(unsigned k) {
    unsigned a = (unsigned)DPP_ROR(k, 1);
    unsigned b = (unsigned)DPP_ROR(k, 2);
    k = umin_(k, umin_(a, b));            // covers offsets 0..2
    a = (unsigned)DPP_ROR(k, 3);
    b = (unsigned)DPP_ROR(k, 6);
    k = umin_(k, umin_(a, b));            // 0..8
    a = (unsigned)DPP_ROR(k, 9);
    k = umin_(k, a);                      // 0..15 (wrap overlap OK for min)
#if __has_builtin(__builtin_amdgcn_permlane16_swap)
    {
        uint32x2_t r = __builtin_amdgcn_permlane16_swap(k, k, false, false);
        k = umin_(r[0], r[1]);
    }
#else
    k = umin_(k, (unsigned)__shfl_xor((int)k, 16));
#endif
#if __has_builtin(__builtin_amdgcn_permlane32_swap)
    {
        uint32x2_t r = __builtin_amdgcn_permlane32_swap(k, k, false, false);
        k = umin_(r[0], r[1]);
    }
#else
    k = umin_(k, (unsigned)__shfl_xor((int)k, 32));
#endif
    return k;
}

// two smallest keys across the wave (disjoint-window rotate-reduce).
__device__ __forceinline__ void wave_kmin2(unsigned& ks, unsigned& kb, int lane) {
    unsigned ps, pb;
#define KM2_COMBINE { unsigned ns = umin_(ks, ps); kb = umin_(umin_(kb, pb), umax_(ks, ps)); ks = ns; }
    ps = (unsigned)DPP_ROR(ks, 1); pb = (unsigned)DPP_ROR(kb, 1); KM2_COMBINE;
    ps = (unsigned)DPP_ROR(ks, 2); pb = (unsigned)DPP_ROR(kb, 2); KM2_COMBINE;
    ps = (unsigned)DPP_ROR(ks, 4); pb = (unsigned)DPP_ROR(kb, 4); KM2_COMBINE;
    ps = (unsigned)DPP_ROR(ks, 8); pb = (unsigned)DPP_ROR(kb, 8); KM2_COMBINE;
    ps = partner16(ks, lane); pb = partner16(kb, lane); KM2_COMBINE;
    ps = partner32(ks, lane); pb = partner32(kb, lane); KM2_COMBINE;
#undef KM2_COMBINE
}

// One block = one batch, 64 threads (1 wave). Lane owns 1-based columns ja=lane+1, jb=lane+65.
__global__ __launch_bounds__(64, 1)
void lsap_kernel(const float* __restrict__ y_true, const float* __restrict__ y_pred,
                 float* __restrict__ batch_sums, float* __restrict__ out, int use_atomic) {
    __shared__ float dist[N * N];            // 64 KB; columns ca/cb touched only by owner lane
    __shared__ float ytl[N * DIM];           // 32 KB
    __shared__ long long pu[N + 1];          // low32 = p[j] (row, 1-based; 0=free), high32 = bits of u[p[j]]
    __shared__ int way[N + 1];
    __shared__ float u_row[N];
    __shared__ int unlist[N + ARR_CAP + 4];

    const int b = blockIdx.x;
    const int lane = threadIdx.x;
    const int ca = lane, cb = lane + 64;
    const int ja = lane + 1, jb = lane + 65;

    // ---- stage y_true[b] into LDS ----
    {
        const float4* yt4 = (const float4*)(y_true + (size_t)b * N * DIM);
        float4* ytl4 = (float4*)ytl;
        for (int k = lane; k < N * DIM / 4; k += 64) ytl4[k] = yt4[k];
    }

    // ---- y_pred rows ca, cb into registers ----
    float ypa[DIM], ypb[DIM];
    {
        const float4* pa4 = (const float4*)(y_pred + (size_t)b * N * DIM + (size_t)ca * DIM);
        const float4* pb4 = (const float4*)(y_pred + (size_t)b * N * DIM + (size_t)cb * DIM);
        #pragma unroll
        for (int k = 0; k < DIM / 4; ++k) {
            float4 v4 = pa4[k];
            ypa[4*k+0]=v4.x; ypa[4*k+1]=v4.y; ypa[4*k+2]=v4.z; ypa[4*k+3]=v4.w;
            float4 w4 = pb4[k];
            ypb[4*k+0]=w4.x; ypb[4*k+1]=w4.y; ypb[4*k+2]=w4.z; ypb[4*k+3]=w4.w;
        }
    }

    pu[ja] = 0; pu[jb] = 0;
    if (lane == 0) pu[0] = 0;
    __syncthreads();   // ytl visible

    // ---- Phase A: dist columns + column minima (v init) ----
    float va = INFINITY, vb = INFINITY;      // v[ja], v[jb] live in registers
    for (int i = 0; i < N; ++i) {
        const float4* yr = (const float4*)(ytl + i * DIM);
        float a0 = 0.f, a1 = 0.f;
        #pragma unroll
        for (int k = 0; k < DIM / 4; ++k) {
            float4 t4 = yr[k];
            float d;
            d = t4.x - ypa[4*k+0]; a0 = fmaf(d, d, a0);
            d = t4.y - ypa[4*k+1]; a0 = fmaf(d, d, a0);
            d = t4.z - ypa[4*k+2]; a0 = fmaf(d, d, a0);
            d = t4.w - ypa[4*k+3]; a0 = fmaf(d, d, a0);
            d = t4.x - ypb[4*k+0]; a1 = fmaf(d, d, a1);
            d = t4.y - ypb[4*k+1]; a1 = fmaf(d, d, a1);
            d = t4.z - ypb[4*k+2]; a1 = fmaf(d, d, a1);
            d = t4.w - ypb[4*k+3]; a1 = fmaf(d, d, a1);
        }
        float d0 = sqrtf(a0), d1 = sqrtf(a1);
        dist[i * N + ca] = d0;
        dist[i * N + cb] = d1;
        va = fminf(va, d0);
        vb = fminf(vb, d1);
    }
    // dist columns are only ever read by their owner lane -> no barrier needed for dist.

    // ---- Phase B+C fused: row minima of reduced costs; greedy assignment ----
    int nun = 0;     // wave-uniform
    for (int r = 0; r < N; ++r) {
        float c0 = dist[r * N + ca] - va;
        float c1 = dist[r * N + cb] - vb;
        float cand = fminf(c0, c1);
        int colm = (c0 <= c1) ? ja : jb;
        unsigned key = (monokey(cand) & ~63u) | (unsigned)lane;
        key = wave_kmin(key);
        int w = (int)(__builtin_amdgcn_readfirstlane((int)key) & 63);
        float g = rl_f(cand, w);
        int js = rl_i(colm, w);
        int owner = (int)pu[js];             // broadcast LDS read
        if (lane == 0) u_row[r] = g;
        if (owner == 0) {
            if (lane == 0) pu[js] = ((long long)__float_as_int(g) << 32) | (unsigned)(r + 1);
        } else {
            if (lane == 0) unlist[nun] = r;
            ++nun;
        }
    }

    // ---- Augmenting row reduction (LAPJV), op-capped ----
    int k = 0, nf = nun, ops = 0, pending = -1;
    while (ops < ARR_CAP) {
        int i;
        if (pending >= 0) { i = pending; pending = -1; }
        else if (k < nf) { i = unlist[k]; ++k; }
        else break;
        ++ops;

        float c0 = dist[i * N + ca] - va;
        float c1 = dist[i * N + cb] - vb;
        unsigned k0 = (monokey(c0) & ~63u) | (unsigned)lane;
        unsigned k1 = (monokey(c1) & ~63u) | (unsigned)lane;
        bool afirst = (k0 <= k1);
        unsigned ks = afirst ? k0 : k1, kb = afirst ? k1 : k0;
        float sm = afirst ? c0 : c1, bg = afirst ? c1 : c0;
        int colm = afirst ? ja : jb, colS = afirst ? jb : ja;
        wave_kmin2(ks, kb, lane);
        int w1 = (int)(__builtin_amdgcn_readfirstlane((int)ks) & 63);
        int w2 = (int)(__builtin_amdgcn_readfirstlane((int)kb) & 63);
        float u1 = rl_f(sm, w1);
        int j1 = rl_i(colm, w1);
        float u2; int j2;
        if (w2 == w1) { u2 = rl_f(bg, w1); j2 = rl_i(colS, w1); }
        else          { u2 = rl_f(sm, w2); j2 = rl_i(colm, w2); }

        long long q1 = pu[j1];
        long long q2 = pu[j2];
        int i0 = (int)q1;
        int jt, it0;
        if (u1 < u2) {
            float dd = u2 - u1;
            if (ja == j1) va -= dd;
            if (jb == j1) vb -= dd;
            jt = j1; it0 = i0;
        } else if (i0 > 0) {
            jt = j2; it0 = (int)q2;
        } else {
            jt = j1; it0 = 0;
        }
        if (lane == 0) {
            pu[jt] = ((long long)__float_as_int(u2) << 32) | (unsigned)(i + 1);
            u_row[i] = u2;
        }
        if (it0 > 0) {
            if (u1 < u2) pending = it0 - 1;
            else { if (lane == 0) unlist[nf] = it0 - 1; ++nf; }
        }
    }
    if (pending >= 0) { --k; if (lane == 0) unlist[k] = pending; }
    __syncthreads();

    // ---- Dijkstra augmenting phases for remaining free rows ----
    for (int t = k; t < nf; ++t) {
        int r = unlist[t];
        long long ta = pu[ja], tb = pu[jb];
        int pa = (int)ta, pb = (int)tb;
        float upa = __int_as_float((int)(ta >> 32));
        float upb = __int_as_float((int)(tb >> 32));
        float mina = INFINITY, minb = INFINITY;
        int useda = 0, usedb = 0, waya = 0, wayb = 0;
        float uacca = 0.f, uaccb = 0.f;
        const float u_i = u_row[r];
        float u_acc_i = u_i;
        int j0 = 0, i0 = r + 1;
        float u0c = u_i;

        for (;;) {
            if (ja == j0) useda = 1;
            if (jb == j0) usedb = 1;
            const float* drow = dist + (i0 - 1) * N;
            float d0 = drow[ca], d1 = drow[cb];
            if (!useda) { float cur = d0 - u0c - va; if (cur < mina) { mina = cur; waya = j0; } }
            if (!usedb) { float cur = d1 - u0c - vb; if (cur < minb) { minb = cur; wayb = j0; } }

            float cand = useda ? INFINITY : mina;
            int cm = ja, pm = pa; float um = upa;
            float candb = usedb ? INFINITY : minb;
            if (candb < cand) { cand = candb; cm = jb; pm = pb; um = upb; }

            unsigned key = (monokey(cand) & ~63u) | (unsigned)lane;
            key = wave_kmin(key);
            int w = (int)(__builtin_amdgcn_readfirstlane((int)key) & 63);
            float delta = rl_f(cand, w);
            int pkj = rl_i((pm << 8) | cm, w);
            float u1v = rl_f(um, w);

            if (useda) { va -= delta; uacca += delta; } else { mina -= delta; }
            if (usedb) { vb -= delta; uaccb += delta; } else { minb -= delta; }
            u_acc_i += delta;

            j0 = pkj & 255;
            int i1 = pkj >> 8;
            if (i1 == 0) break;
            i0 = i1; u0c = u1v;
        }

        way[ja] = waya; way[jb] = wayb;
        {
            int* pui = (int*)pu;
            if (useda) pui[2 * ja + 1] = __float_as_int(upa + uacca);
            if (usedb) pui[2 * jb + 1] = __float_as_int(upb + uaccb);
        }
        __syncthreads();
        if (lane == 0) {
            int jj = j0;
            for (;;) {
                int jp = way[jj];
                if (jp == 0) {
                    pu[jj] = ((long long)__float_as_int(u_acc_i) << 32) | (unsigned)(r + 1);
                    break;
                }
                pu[jj] = pu[jp];
                jj = jp;
            }
        }
        __syncthreads();
    }
    __syncthreads();

    // ---- matched sum ----
    long long ta = pu[ja], tb = pu[jb];
    int pa = (int)ta, pb = (int)tb;
    float s = dist[(pa - 1) * N + ca] + dist[(pb - 1) * N + cb];
    #pragma unroll
    for (int m = 1; m < 64; m <<= 1) s += __shfl_xor(s, m);
    if (lane == 0) {
        if (use_atomic) atomicAdd(out, s * (1.0f / (float)BATCH));
        else batch_sums[b] = s;
    }
}

__global__ __launch_bounds__(64)
void reduce_kernel(const float* __restrict__ bs, float* __restrict__ out) {
    int tid = threadIdx.x;
    float v = bs[tid];
    #pragma unroll
    for (int m = 1; m < 64; m <<= 1) v += __shfl_xor(v, m);
    if (tid == 0) out[0] = v * (1.0f / (float)BATCH);
}

extern "C" void kernel_launch(void* const* d_in, const int* in_sizes, int n_in,
                              void* d_out, int out_size, void* d_ws, size_t ws_size,
                              hipStream_t stream) {
    const float* y_true = (const float*)d_in[0];
    const float* y_pred = (const float*)d_in[1];
    float* out = (float*)d_out;

    if (ws_size >= BATCH * sizeof(float)) {
        float* bs = (float*)d_ws;
        lsap_kernel<<<BATCH, 64, 0, stream>>>(y_true, y_pred, bs, out, 0);
        reduce_kernel<<<1, 64, 0, stream>>>(bs, out);
    } else {
        hipMemsetAsync(d_out, 0, sizeof(float), stream);
        lsap_kernel<<<BATCH, 64, 0, stream>>>(y_true, y_pred, nullptr, out, 1);
    }
}